// Round 1
// baseline (1176.792 us; speedup 1.0000x reference)
//
#include <hip/hip_runtime.h>
#include <math.h>

#define NTOK 8192
#define NEMB 8192
#define DIM  256
#define NSEG 8
#define ESEG (NEMB / NSEG)   // 1024 codes per segment
#define TM   128             // tokens per block
#define TE   128             // codes per e-tile
#define KT   32              // k-chunk staged in LDS

// ---------------------------------------------------------------------------
// Kernel 0: exact ||c||^2 per codebook row (fp32). 4 waves/block, 4 codes/wave.
__global__ __launch_bounds__(256) void cnorm_kernel(const float* __restrict__ C,
                                                    float* __restrict__ cnorm) {
    int w = blockIdx.x * 4 + (threadIdx.x >> 6);
    int lane = threadIdx.x & 63;
    #pragma unroll
    for (int i = 0; i < 4; ++i) {
        int e = w * 4 + i;
        float4 c = *(const float4*)&C[(size_t)e * DIM + lane * 4];
        float s = c.x * c.x + c.y * c.y + c.z * c.z + c.w * c.w;
        #pragma unroll
        for (int off = 32; off >= 1; off >>= 1) s += __shfl_xor(s, off);
        if (lane == 0) cnorm[e] = s;
    }
}

// ---------------------------------------------------------------------------
// Kernel 1: fused distance GEMM + per-segment argmin.
// Block: 256 threads as (tx 0..15, ty 0..15). Thread tile: 8 tokens x 8 codes.
// Block tile: 128 tokens x 128 codes, looping over a 1024-code segment.
// LDS float4 granules XOR-swizzled by (row>>3)&7 to break the 128B-row-stride
// bank aliasing (every row starts at bank 0 otherwise).
__global__ __launch_bounds__(256) void dist_argmin_kernel(
        const float* __restrict__ X, const float* __restrict__ C,
        const float* __restrict__ cnorm,
        float* __restrict__ seg_minv, int* __restrict__ seg_mini) {
    __shared__ float4 Xs[TM * (KT / 4)];   // [row][k4] swizzled, 16 KB
    __shared__ float4 Cs[TE * (KT / 4)];   // 16 KB

    const int t  = threadIdx.x;
    const int tx = t & 15, ty = t >> 4;
    const int m0 = blockIdx.x * TM;
    const int seg = blockIdx.y;
    const int e0 = seg * ESEG;

    float minv[8];
    int   mini[8];
    #pragma unroll
    for (int j = 0; j < 8; ++j) { minv[j] = 1e30f; mini[j] = 0x7fffffff; }

    for (int et = 0; et < ESEG / TE; ++et) {
        const int eb = e0 + et * TE;
        float acc[8][8];
        #pragma unroll
        for (int j = 0; j < 8; ++j)
            #pragma unroll
            for (int l = 0; l < 8; ++l) acc[j][l] = 0.0f;

        for (int kt = 0; kt < DIM / KT; ++kt) {
            const int k0 = kt * KT;
            __syncthreads();
            const float* Xg = X + (size_t)m0 * DIM + k0;
            const float* Cg = C + (size_t)eb * DIM + k0;
            #pragma unroll
            for (int i = 0; i < 4; ++i) {       // stage X tile: 1024 float4
                int f = i * 256 + t;
                int row = f >> 3, k4 = f & 7;
                float4 v = *(const float4*)(Xg + (size_t)row * DIM + k4 * 4);
                Xs[row * 8 + (k4 ^ ((row >> 3) & 7))] = v;
            }
            #pragma unroll
            for (int i = 0; i < 4; ++i) {       // stage C tile: 1024 float4
                int f = i * 256 + t;
                int row = f >> 3, k4 = f & 7;
                float4 v = *(const float4*)(Cg + (size_t)row * DIM + k4 * 4);
                Cs[row * 8 + (k4 ^ ((row >> 3) & 7))] = v;
            }
            __syncthreads();

            #pragma unroll
            for (int k4 = 0; k4 < KT / 4; ++k4) {
                const int sa = k4 ^ (ty & 7);   // (ty*8+j)>>3 == ty for j<8
                const int sb = k4 ^ (tx & 7);
                float4 a[8];
                #pragma unroll
                for (int j = 0; j < 8; ++j) a[j] = Xs[(ty * 8 + j) * 8 + sa];
                #pragma unroll
                for (int l = 0; l < 8; ++l) {
                    float4 b = Cs[(tx * 8 + l) * 8 + sb];
                    #pragma unroll
                    for (int j = 0; j < 8; ++j) {
                        acc[j][l] += a[j].x * b.x + a[j].y * b.y
                                   + a[j].z * b.z + a[j].w * b.w;
                    }
                }
            }
        }

        // fold this e-tile into the running per-thread argmin
        float cn[8];
        {
            float4 c0 = *(const float4*)&cnorm[eb + tx * 8];
            float4 c1 = *(const float4*)&cnorm[eb + tx * 8 + 4];
            cn[0] = c0.x; cn[1] = c0.y; cn[2] = c0.z; cn[3] = c0.w;
            cn[4] = c1.x; cn[5] = c1.y; cn[6] = c1.z; cn[7] = c1.w;
        }
        #pragma unroll
        for (int j = 0; j < 8; ++j) {
            #pragma unroll
            for (int l = 0; l < 8; ++l) {
                float d = cn[l] - 2.0f * acc[j][l];   // ||c||^2 - 2 x.c
                int e = eb + tx * 8 + l;              // ascending -> strict <
                if (d < minv[j]) { minv[j] = d; mini[j] = e; }
            }
        }
    }

    // reduce across the 16 tx lanes (lanes [ty%4]*16 .. +15 within a wave)
    #pragma unroll
    for (int j = 0; j < 8; ++j) {
        float v = minv[j]; int bi = mini[j];
        #pragma unroll
        for (int off = 8; off >= 1; off >>= 1) {
            float ov = __shfl_xor(v, off);
            int   oi = __shfl_xor(bi, off);
            if (ov < v || (ov == v && oi < bi)) { v = ov; bi = oi; }
        }
        if (tx == 0) {
            int token = m0 + ty * 8 + j;
            seg_minv[(size_t)token * NSEG + seg] = v;
            seg_mini[(size_t)token * NSEG + seg] = bi;
        }
    }
}

// ---------------------------------------------------------------------------
// Kernel 2: fold the NSEG candidates per token; histogram.
__global__ __launch_bounds__(256) void reduce_idx_kernel(
        const float* __restrict__ seg_minv, const int* __restrict__ seg_mini,
        int* __restrict__ idx, int* __restrict__ counts) {
    int token = blockIdx.x * 256 + threadIdx.x;
    float bv = 1e30f; int bi = 0x7fffffff;
    #pragma unroll
    for (int s = 0; s < NSEG; ++s) {
        float v = seg_minv[(size_t)token * NSEG + s];
        int   i = seg_mini[(size_t)token * NSEG + s];
        if (v < bv || (v == bv && i < bi)) { bv = v; bi = i; }
    }
    idx[token] = bi;
    atomicAdd(&counts[bi], 1);
}

// ---------------------------------------------------------------------------
// Kernel 3: gather codebook rows -> out, accumulate sum((q-x)^2).
// One wave per 2 tokens: lane owns 4 contiguous floats of the 256-dim row.
__global__ __launch_bounds__(256) void gather_loss_kernel(
        const float* __restrict__ X, const float* __restrict__ C,
        const int* __restrict__ idx, float* __restrict__ out,
        float* __restrict__ sumsq) {
    int wave = blockIdx.x * 4 + (threadIdx.x >> 6);
    int lane = threadIdx.x & 63;
    float local = 0.0f;
    #pragma unroll
    for (int i = 0; i < 2; ++i) {
        int token = wave * 2 + i;
        int e = idx[token];
        float4 q = *(const float4*)&C[(size_t)e * DIM + lane * 4];
        float4 x = *(const float4*)&X[(size_t)token * DIM + lane * 4];
        *(float4*)&out[(size_t)token * DIM + lane * 4] = q;
        float d0 = q.x - x.x, d1 = q.y - x.y, d2 = q.z - x.z, d3 = q.w - x.w;
        local += d0 * d0 + d1 * d1 + d2 * d2 + d3 * d3;
    }
    #pragma unroll
    for (int off = 32; off >= 1; off >>= 1) local += __shfl_xor(local, off);
    if (lane == 0) atomicAdd(sumsq, local);
}

// ---------------------------------------------------------------------------
// Kernel 4: loss + perplexity scalars.
__global__ __launch_bounds__(256) void finalize_kernel(
        const int* __restrict__ counts, const float* __restrict__ sumsq,
        float* __restrict__ out) {
    double local = 0.0;
    for (int e = threadIdx.x; e < NEMB; e += 256) {
        float p = (float)counts[e] * (1.0f / (float)NTOK);
        local += (double)(p * logf(p + 1e-10f));
    }
    #pragma unroll
    for (int off = 32; off >= 1; off >>= 1) local += __shfl_xor(local, off);
    __shared__ double sh[4];
    int lane = threadIdx.x & 63, wid = threadIdx.x >> 6;
    if (lane == 0) sh[wid] = local;
    __syncthreads();
    if (threadIdx.x == 0) {
        double tot = sh[0] + sh[1] + sh[2] + sh[3];
        out[(size_t)NTOK * DIM]     = 1.25f * sumsq[0] / (float)((size_t)NTOK * DIM);
        out[(size_t)NTOK * DIM + 1] = expf((float)(-tot));
    }
}

// ---------------------------------------------------------------------------
extern "C" void kernel_launch(void* const* d_in, const int* in_sizes, int n_in,
                              void* d_out, int out_size, void* d_ws, size_t ws_size,
                              hipStream_t stream) {
    const float* X = (const float*)d_in[0];   // [32,256,256] fp32
    const float* C = (const float*)d_in[1];   // [8192,256]   fp32
    float* out = (float*)d_out;               // 2097152 + 2 fp32

    char* ws = (char*)d_ws;
    float* cnorm    = (float*)(ws);                                  // 32 KB
    float* seg_minv = (float*)(ws + 32768);                          // 256 KB
    int*   seg_mini = (int*)  (ws + 32768 + 262144);                 // 256 KB
    int*   idx      = (int*)  (ws + 32768 + 262144 + 262144);        // 32 KB
    int*   counts   = (int*)  (ws + 32768 + 262144 + 262144 + 32768);// 32 KB
    float* sumsq    = (float*)(ws + 32768 + 262144 + 262144 + 32768 + 32768);

    // counts + sumsq are contiguous: one async memset (ws is poisoned 0xAA).
    hipMemsetAsync(counts, 0, NEMB * sizeof(int) + sizeof(float), stream);

    cnorm_kernel<<<NEMB / 16, 256, 0, stream>>>(C, cnorm);
    dist_argmin_kernel<<<dim3(NTOK / TM, NSEG), 256, 0, stream>>>(
        X, C, cnorm, seg_minv, seg_mini);
    reduce_idx_kernel<<<NTOK / 256, 256, 0, stream>>>(seg_minv, seg_mini, idx, counts);
    gather_loss_kernel<<<NTOK / 8, 256, 0, stream>>>(X, C, idx, out, sumsq);
    finalize_kernel<<<1, 256, 0, stream>>>(counts, sumsq, out);
}